// Round 1
// baseline (1558.929 us; speedup 1.0000x reference)
//
#include <hip/hip_runtime.h>
#include <math.h>

// Problem constants (fixed shapes from setup_inputs)
#define B_C   4096   // comments
#define N_SRT 8192   // srt rows
#define D_C   768
#define D_S   1024
#define KSEL  2
#define NSLICE 8     // N partitioned into 8 slices of 1024 for the scores kernel

// ---------------------------------------------------------------------------
// Kernel 1: C = relu(A @ B + bias);  A[M,K] row-major, B[K,N] row-major.
// 64x64 tile, BK=16, 256 threads, 4x4 micro-tile per thread, fp32.
// ---------------------------------------------------------------------------
__global__ __launch_bounds__(256)
void gemm_bias_relu(const float* __restrict__ A, const float* __restrict__ Bm,
                    const float* __restrict__ bias, float* __restrict__ C,
                    int M, int N, int K) {
    __shared__ float As[16][64];   // [k][m]
    __shared__ float Bs[16][64];   // [k][n]
    const int tid = threadIdx.x;
    const int tx = tid & 15, ty = tid >> 4;
    const int bm = blockIdx.y * 64, bn = blockIdx.x * 64;

    float acc[4][4] = {};

    for (int k0 = 0; k0 < K; k0 += 16) {
        // A tile 64x16 -> As[k][m]; each thread one float4 along K
        {
            const int r  = tid >> 2;
            const int kk = (tid & 3) * 4;
            const float4 v = *reinterpret_cast<const float4*>(&A[(size_t)(bm + r) * K + k0 + kk]);
            As[kk + 0][r] = v.x; As[kk + 1][r] = v.y;
            As[kk + 2][r] = v.z; As[kk + 3][r] = v.w;
        }
        // B tile 16x64 -> Bs[k][n]
        {
            const int kk = tid >> 4;
            const int c  = (tid & 15) * 4;
            *reinterpret_cast<float4*>(&Bs[kk][c]) =
                *reinterpret_cast<const float4*>(&Bm[(size_t)(k0 + kk) * N + bn + c]);
        }
        __syncthreads();
#pragma unroll
        for (int kk = 0; kk < 16; ++kk) {
            const float4 a = *reinterpret_cast<const float4*>(&As[kk][ty * 4]);
            const float4 b = *reinterpret_cast<const float4*>(&Bs[kk][tx * 4]);
            const float av[4] = {a.x, a.y, a.z, a.w};
            const float bv[4] = {b.x, b.y, b.z, b.w};
#pragma unroll
            for (int i = 0; i < 4; ++i)
#pragma unroll
                for (int j = 0; j < 4; ++j)
                    acc[i][j] = fmaf(av[i], bv[j], acc[i][j]);
        }
        __syncthreads();
    }

#pragma unroll
    for (int i = 0; i < 4; ++i) {
        const int r = bm + ty * 4 + i;
        const int c = bn + tx * 4;
        float4 o;
        o.x = fmaxf(acc[i][0] + bias[c + 0], 0.f);
        o.y = fmaxf(acc[i][1] + bias[c + 1], 0.f);
        o.z = fmaxf(acc[i][2] + bias[c + 2], 0.f);
        o.w = fmaxf(acc[i][3] + bias[c + 3], 0.f);
        *reinterpret_cast<float4*>(&C[(size_t)r * N + c]) = o;
    }
}

// ---------------------------------------------------------------------------
// Kernel 2: scores (TC @ TS^T) for one 64-comment block x one 1024-srt slice,
// fp32, with fused online top-2 per comment row. Partial (v1,i1,v2,i2) per
// row per slice written to workspace. Scan order is strictly increasing n,
// strict '>' comparisons => lowest-index-first on ties (matches lax.top_k).
// ---------------------------------------------------------------------------
__global__ __launch_bounds__(256)
void scores_top2_partial(const float* __restrict__ TC,  // [B_C, D_S]
                         const float* __restrict__ TS,  // [N_SRT, D_S]
                         float* __restrict__ part) {    // [B_C, NSLICE, 4]
    __shared__ float As[16][64];   // [k][comment]
    __shared__ float Bs[16][64];   // [k][srt]
    __shared__ float Sc[64][65];   // score tile (padded)

    const int tid = threadIdx.x;
    const int tx = tid & 15, ty = tid >> 4;
    const int bm    = blockIdx.y * 64;          // comment block
    const int slice = blockIdx.x;               // n slice (1024 wide)
    const int nbase = slice * (N_SRT / NSLICE);

    float v1 = -INFINITY, v2 = -INFINITY;
    int   i1 = 0, i2 = 0;

    for (int t = 0; t < (N_SRT / NSLICE) / 64; ++t) {
        const int n0 = nbase + t * 64;
        float acc[4][4] = {};
        for (int k0 = 0; k0 < D_S; k0 += 16) {
            {
                const int r  = tid >> 2;
                const int kk = (tid & 3) * 4;
                const float4 v = *reinterpret_cast<const float4*>(&TC[(size_t)(bm + r) * D_S + k0 + kk]);
                As[kk + 0][r] = v.x; As[kk + 1][r] = v.y;
                As[kk + 2][r] = v.z; As[kk + 3][r] = v.w;
                const float4 w = *reinterpret_cast<const float4*>(&TS[(size_t)(n0 + r) * D_S + k0 + kk]);
                Bs[kk + 0][r] = w.x; Bs[kk + 1][r] = w.y;
                Bs[kk + 2][r] = w.z; Bs[kk + 3][r] = w.w;
            }
            __syncthreads();
#pragma unroll
            for (int kk = 0; kk < 16; ++kk) {
                const float4 a = *reinterpret_cast<const float4*>(&As[kk][ty * 4]);
                const float4 b = *reinterpret_cast<const float4*>(&Bs[kk][tx * 4]);
                const float av[4] = {a.x, a.y, a.z, a.w};
                const float bv[4] = {b.x, b.y, b.z, b.w};
#pragma unroll
                for (int i = 0; i < 4; ++i)
#pragma unroll
                    for (int j = 0; j < 4; ++j)
                        acc[i][j] = fmaf(av[i], bv[j], acc[i][j]);
            }
            __syncthreads();
        }
        // stash tile, then per-row serial scan in increasing n order
#pragma unroll
        for (int i = 0; i < 4; ++i)
#pragma unroll
            for (int j = 0; j < 4; ++j)
                Sc[ty * 4 + i][tx * 4 + j] = acc[i][j];
        __syncthreads();
        if (tid < 64) {
            for (int j = 0; j < 64; ++j) {
                const float v = Sc[tid][j];
                const int   n = n0 + j;
                if (v > v1)      { v2 = v1; i2 = i1; v1 = v; i1 = n; }
                else if (v > v2) { v2 = v;  i2 = n; }
            }
        }
        __syncthreads();
    }

    if (tid < 64) {
        float* p = &part[((size_t)(bm + tid) * NSLICE + slice) * 4];
        p[0] = v1; p[1] = __int_as_float(i1);
        p[2] = v2; p[3] = __int_as_float(i2);
    }
}

// ---------------------------------------------------------------------------
// Kernel 3: merge NSLICE partial top-2 sets per row -> final indices.
// Slices visited in increasing n order; same strict '>' rule keeps
// lowest-index-first tie semantics.
// ---------------------------------------------------------------------------
__global__ __launch_bounds__(256)
void merge_top2(const float* __restrict__ part, int* __restrict__ topIdx) {
    const int b = blockIdx.x * 256 + threadIdx.x;
    if (b >= B_C) return;
    float v1 = -INFINITY, v2 = -INFINITY;
    int   i1 = 0, i2 = 0;
#pragma unroll
    for (int s = 0; s < NSLICE; ++s) {
        const float* p = &part[((size_t)b * NSLICE + s) * 4];
        const float pv1 = p[0]; const int pi1 = __float_as_int(p[1]);
        const float pv2 = p[2]; const int pi2 = __float_as_int(p[3]);
        if (pv1 > v1)      { v2 = v1; i2 = i1; v1 = pv1; i1 = pi1; }
        else if (pv1 > v2) { v2 = pv1; i2 = pi1; }
        if (pv2 > v1)      { v2 = v1; i2 = i1; v1 = pv2; i1 = pi2; }
        else if (pv2 > v2) { v2 = pv2; i2 = pi2; }
    }
    topIdx[b * 2 + 0] = i1;
    topIdx[b * 2 + 1] = i2;
}

// ---------------------------------------------------------------------------
// Kernel 4: gather selected transformed-srt rows -> output [B_C, 2, D_S].
// ---------------------------------------------------------------------------
__global__ __launch_bounds__(256)
void gather_rows(const float* __restrict__ TS, const int* __restrict__ topIdx,
                 float* __restrict__ out) {
    const int row = blockIdx.x;              // 0 .. B_C*KSEL-1
    const int src = topIdx[row];
    const int tid = threadIdx.x;
    const float4 v = *reinterpret_cast<const float4*>(&TS[(size_t)src * D_S + tid * 4]);
    *reinterpret_cast<float4*>(&out[(size_t)row * D_S + tid * 4]) = v;
}

// ---------------------------------------------------------------------------
extern "C" void kernel_launch(void* const* d_in, const int* in_sizes, int n_in,
                              void* d_out, int out_size, void* d_ws, size_t ws_size,
                              hipStream_t stream) {
    const float* srt      = (const float*)d_in[0];  // [8192,1024]
    const float* comments = (const float*)d_in[1];  // [4096,768]
    const float* Wc       = (const float*)d_in[2];  // [768,1024]
    const float* bc       = (const float*)d_in[3];  // [1024]
    const float* Ws       = (const float*)d_in[4];  // [1024,1024]
    const float* bs       = (const float*)d_in[5];  // [1024]
    float* out = (float*)d_out;

    // workspace layout
    float* t_c  = (float*)d_ws;                          // 4096*1024
    float* t_s  = t_c + (size_t)B_C * D_S;               // 8192*1024
    float* part = t_s + (size_t)N_SRT * D_S;             // 4096*8*4
    int*   tidx = (int*)(part + (size_t)B_C * NSLICE * 4); // 4096*2

    // transforms (fp32 exact — index selection depends on these)
    gemm_bias_relu<<<dim3(D_S / 64, B_C / 64), 256, 0, stream>>>(
        comments, Wc, bc, t_c, B_C, D_S, D_C);
    gemm_bias_relu<<<dim3(D_S / 64, N_SRT / 64), 256, 0, stream>>>(
        srt, Ws, bs, t_s, N_SRT, D_S, D_S);

    // fused scores + online top-2 (softmax skipped: monotone)
    scores_top2_partial<<<dim3(NSLICE, B_C / 64), 256, 0, stream>>>(t_c, t_s, part);

    // merge partials, gather output rows
    merge_top2<<<dim3(B_C / 256), 256, 0, stream>>>(part, tidx);
    gather_rows<<<dim3(B_C * KSEL), 256, 0, stream>>>(t_s, tidx, out);
}

// Round 2
// 518.067 us; speedup vs baseline: 3.0091x; 3.0091x over previous
//
#include <hip/hip_runtime.h>
#include <math.h>

#define B_C   4096   // comments
#define N_SRT 8192   // srt rows
#define D_C   768
#define D_S   1024
#define KSEL  2
#define NGRP  (N_SRT / 4)   // 2048 groups of 4 consecutive srt rows
#define PGRP  8             // groups refined per comment row (32 candidates)

typedef float  f32x4  __attribute__((ext_vector_type(4)));
typedef short  short8 __attribute__((ext_vector_type(8)));

__device__ inline unsigned short f2bf(float f) {           // RTNE float->bf16
    unsigned u = __float_as_uint(f);
    u += 0x7FFF + ((u >> 16) & 1);
    return (unsigned short)(u >> 16);
}
__device__ inline float bf2f(unsigned short h) {
    return __uint_as_float(((unsigned)h) << 16);
}

#define GLOAD_LDS16(gsrc, ldst)                                                     \
    __builtin_amdgcn_global_load_lds(                                               \
        (const __attribute__((address_space(1))) void*)(gsrc),                      \
        (__attribute__((address_space(3))) void*)(ldst), 16, 0, 0)

// ---------------------------------------------------------------------------
// Kernel 1: C = relu(A @ B + bias), fp32; also writes bf16 copy for the
// MFMA filter. 64x64 tile, BK=16, 256 threads, 4x4 micro-tile.
// ---------------------------------------------------------------------------
__global__ __launch_bounds__(256)
void gemm_bias_relu_dual(const float* __restrict__ A, const float* __restrict__ Bm,
                         const float* __restrict__ bias, float* __restrict__ C,
                         unsigned short* __restrict__ Ch,
                         int M, int N, int K) {
    __shared__ float As[16][64];   // [k][m]
    __shared__ float Bs[16][64];   // [k][n]
    const int tid = threadIdx.x;
    const int tx = tid & 15, ty = tid >> 4;
    const int bm = blockIdx.y * 64, bn = blockIdx.x * 64;

    float acc[4][4] = {};

    for (int k0 = 0; k0 < K; k0 += 16) {
        {
            const int r  = tid >> 2;
            const int kk = (tid & 3) * 4;
            const float4 v = *reinterpret_cast<const float4*>(&A[(size_t)(bm + r) * K + k0 + kk]);
            As[kk + 0][r] = v.x; As[kk + 1][r] = v.y;
            As[kk + 2][r] = v.z; As[kk + 3][r] = v.w;
        }
        {
            const int kk = tid >> 4;
            const int c  = (tid & 15) * 4;
            *reinterpret_cast<float4*>(&Bs[kk][c]) =
                *reinterpret_cast<const float4*>(&Bm[(size_t)(k0 + kk) * N + bn + c]);
        }
        __syncthreads();
#pragma unroll
        for (int kk = 0; kk < 16; ++kk) {
            const float4 a = *reinterpret_cast<const float4*>(&As[kk][ty * 4]);
            const float4 b = *reinterpret_cast<const float4*>(&Bs[kk][tx * 4]);
            const float av[4] = {a.x, a.y, a.z, a.w};
            const float bv[4] = {b.x, b.y, b.z, b.w};
#pragma unroll
            for (int i = 0; i < 4; ++i)
#pragma unroll
                for (int j = 0; j < 4; ++j)
                    acc[i][j] = fmaf(av[i], bv[j], acc[i][j]);
        }
        __syncthreads();
    }

#pragma unroll
    for (int i = 0; i < 4; ++i) {
        const int r = bm + ty * 4 + i;
        const int c = bn + tx * 4;
        float4 o;
        o.x = fmaxf(acc[i][0] + bias[c + 0], 0.f);
        o.y = fmaxf(acc[i][1] + bias[c + 1], 0.f);
        o.z = fmaxf(acc[i][2] + bias[c + 2], 0.f);
        o.w = fmaxf(acc[i][3] + bias[c + 3], 0.f);
        *reinterpret_cast<float4*>(&C[(size_t)r * N + c]) = o;
        ushort4 h;
        h.x = f2bf(o.x); h.y = f2bf(o.y); h.z = f2bf(o.z); h.w = f2bf(o.w);
        *reinterpret_cast<ushort4*>(&Ch[(size_t)r * N + c]) = h;
    }
}

// ---------------------------------------------------------------------------
// Kernel 2: bf16 MFMA score filter. Block = 128 srt x 128 comments, 4 waves
// (2x2), each wave a 64x64 tile (4x4 frags of 16x16x32 MFMA). BK=64, LDS
// XOR-swizzled via pre-swizzled global_load_lds sources (both-sides rule).
// Emits per-(comment, 4-wide-n-group) max into G[B_C][NGRP] (bf16).
// acc[nt][ct]: rows n = n0+wn*64+nt*16+(lane>>4)*4+j, col c = c0+wc*64+ct*16+(lane&15)
// (C/D layout HW-verified: col=lane&15, row=(lane>>4)*4+reg). A/B k-slot
// mapping identical for both operands => dot exact under any HW k-permutation.
// ---------------------------------------------------------------------------
__global__ __launch_bounds__(256)
void scores_filter(const unsigned short* __restrict__ TSh,  // [N_SRT][D_S] bf16
                   const unsigned short* __restrict__ TCh,  // [B_C][D_S] bf16
                   unsigned short* __restrict__ G) {        // [B_C][NGRP] bf16
    __shared__ __align__(16) unsigned short sA[128 * 64];   // TS chunk, swizzled
    __shared__ __align__(16) unsigned short sB[128 * 64];   // TC chunk, swizzled
    const int tid  = threadIdx.x;
    const int lane = tid & 63;
    const int w    = tid >> 6;
    const int lr   = lane & 15, lg = lane >> 4;
    const int wn   = w & 1, wc = w >> 1;
    const int n0   = blockIdx.x * 128;
    const int c0   = blockIdx.y * 128;

    const f32x4 vzero = {0.f, 0.f, 0.f, 0.f};
    f32x4 acc[4][4];
#pragma unroll
    for (int i = 0; i < 4; ++i)
#pragma unroll
        for (int j = 0; j < 4; ++j) acc[i][j] = vzero;

    const int sr = tid >> 3;  // staging row within 32-row stripe
    const int sb = tid & 7;   // 16B block within 128B row

    for (int kc = 0; kc < 16; ++kc) {
        const int kb = kc * 64;
        __syncthreads();
#pragma unroll
        for (int i = 0; i < 4; ++i) {
            const int r  = i * 32 + sr;
            const int sw = (sb ^ (r & 7)) * 8;    // inverse-swizzled k element offset
            GLOAD_LDS16(TSh + (size_t)(n0 + r) * D_S + kb + sw,
                        (char*)sA + i * 4096 + tid * 16);
            GLOAD_LDS16(TCh + (size_t)(c0 + r) * D_S + kb + sw,
                        (char*)sB + i * 4096 + tid * 16);
        }
        __syncthreads();
#pragma unroll
        for (int kt = 0; kt < 2; ++kt) {
            short8 a[4], b[4];
#pragma unroll
            for (int t = 0; t < 4; ++t) {
                const int ra = wn * 64 + t * 16 + lr;
                a[t] = *(const short8*)((const char*)sA + ra * 128 +
                                        (((kt * 4 + lg) ^ (ra & 7)) * 16));
                const int rb = wc * 64 + t * 16 + lr;
                b[t] = *(const short8*)((const char*)sB + rb * 128 +
                                        (((kt * 4 + lg) ^ (rb & 7)) * 16));
            }
#pragma unroll
            for (int i = 0; i < 4; ++i)
#pragma unroll
                for (int j = 0; j < 4; ++j)
                    acc[i][j] = __builtin_amdgcn_mfma_f32_16x16x32_bf16(
                        a[i], b[j], acc[i][j], 0, 0, 0);
        }
    }

    // extraction: per-lane j-run is 4 consecutive n => natural 4-wide group max
#pragma unroll
    for (int nt = 0; nt < 4; ++nt) {
        const int n4 = (n0 >> 2) + wn * 16 + nt * 4 + lg;
#pragma unroll
        for (int ct = 0; ct < 4; ++ct) {
            const int c = c0 + wc * 64 + ct * 16 + lr;
            const f32x4 v = acc[nt][ct];
            const float m = fmaxf(fmaxf(v.x, v.y), fmaxf(v.z, v.w));
            G[(size_t)c * NGRP + n4] = f2bf(m);
        }
    }
}

// ---------------------------------------------------------------------------
// Kernel 3: per comment row, top-8 groups by approx group-max (one wave/row).
// 8 rounds of wave-argmax with total-order (value desc, index asc); masking
// via "ranks strictly after previous winner". Output sorted ascending.
// ---------------------------------------------------------------------------
__global__ __launch_bounds__(256)
void top_groups(const unsigned short* __restrict__ G, int* __restrict__ g8) {
    const int w = threadIdx.x >> 6, lane = threadIdx.x & 63;
    const int row = blockIdx.x * 4 + w;
    float v[32];
    const unsigned short* gp = G + (size_t)row * NGRP + lane * 32;
#pragma unroll
    for (int i = 0; i < 4; ++i) {
        short8 h = *(const short8*)(gp + i * 8);
#pragma unroll
        for (int j = 0; j < 8; ++j) v[i * 8 + j] = bf2f((unsigned short)h[j]);
    }
    float pv = INFINITY; int pi = -1;   // previous winner in total order
    int gl[8];
#pragma unroll
    for (int k = 0; k < 8; ++k) {
        float bv = -INFINITY; int bi = NGRP;
#pragma unroll
        for (int i = 0; i < 32; ++i) {
            const int idx = lane * 32 + i;
            const bool after  = (v[i] < pv) || (v[i] == pv && idx > pi);
            const bool before = (v[i] > bv) || (v[i] == bv && idx < bi);
            if (after && before) { bv = v[i]; bi = idx; }
        }
#pragma unroll
        for (int off = 32; off >= 1; off >>= 1) {
            const float ov = __shfl_xor(bv, off);
            const int   oi = __shfl_xor(bi, off);
            if ((ov > bv) || (ov == bv && oi < bi)) { bv = ov; bi = oi; }
        }
        gl[k] = bi; pv = bv; pi = bi;
    }
    // bubble sort ascending (static indices)
#pragma unroll
    for (int a = 0; a < 8; ++a)
#pragma unroll
        for (int b2 = 0; b2 < 7; ++b2)
            if (gl[b2] > gl[b2 + 1]) { int t = gl[b2]; gl[b2] = gl[b2 + 1]; gl[b2 + 1] = t; }
    if (lane == 0) {
        int4 lo = make_int4(gl[0], gl[1], gl[2], gl[3]);
        int4 hi = make_int4(gl[4], gl[5], gl[6], gl[7]);
        *reinterpret_cast<int4*>(g8 + (size_t)row * 8)     = lo;
        *reinterpret_cast<int4*>(g8 + (size_t)row * 8 + 4) = hi;
    }
}

// ---------------------------------------------------------------------------
// Kernel 4: exact fp32 refine of the 32 candidates per row -> top-2 indices.
// One block per comment row; wave per 2 groups; candidates scanned in
// ascending n with strict '>' (matches lax.top_k lowest-index tie rule).
// ---------------------------------------------------------------------------
__global__ __launch_bounds__(256)
void refine(const float* __restrict__ t_c, const float* __restrict__ t_s,
            const int* __restrict__ g8, int* __restrict__ tidx) {
    __shared__ float tc[D_S];
    __shared__ float sc[4 * PGRP];
    const int row = blockIdx.x;
    const int tid = threadIdx.x;
    *reinterpret_cast<float4*>(&tc[tid * 4]) =
        *reinterpret_cast<const float4*>(&t_c[(size_t)row * D_S + tid * 4]);
    __syncthreads();
    const int w = tid >> 6, lane = tid & 63;
    float4 c4[4];
#pragma unroll
    for (int q = 0; q < 4; ++q)
        c4[q] = *reinterpret_cast<const float4*>(&tc[lane * 16 + q * 4]);
#pragma unroll
    for (int i = 0; i < 2; ++i) {
        const int slotg = w * 2 + i;
        const int g = g8[(size_t)row * 8 + slotg];
#pragma unroll
        for (int o = 0; o < 4; ++o) {
            const int n = g * 4 + o;
            const float* ts = t_s + (size_t)n * D_S + lane * 16;
            float p = 0.f;
#pragma unroll
            for (int q = 0; q < 4; ++q) {
                const float4 tv = *reinterpret_cast<const float4*>(ts + q * 4);
                p += c4[q].x * tv.x + c4[q].y * tv.y + c4[q].z * tv.z + c4[q].w * tv.w;
            }
#pragma unroll
            for (int off = 32; off >= 1; off >>= 1) p += __shfl_xor(p, off);
            if (lane == 0) sc[slotg * 4 + o] = p;
        }
    }
    __syncthreads();
    if (tid == 0) {
        float v1 = -INFINITY, v2 = -INFINITY; int i1 = 0, i2 = 0;
#pragma unroll
        for (int s = 0; s < 4 * PGRP; ++s) {
            const int n = g8[(size_t)row * 8 + (s >> 2)] * 4 + (s & 3);
            const float v = sc[s];
            if (v > v1)      { v2 = v1; i2 = i1; v1 = v; i1 = n; }
            else if (v > v2) { v2 = v; i2 = n; }
        }
        tidx[row * 2 + 0] = i1;
        tidx[row * 2 + 1] = i2;
    }
}

// ---------------------------------------------------------------------------
// Kernel 5: gather selected transformed-srt rows -> output [B_C, 2, D_S].
// ---------------------------------------------------------------------------
__global__ __launch_bounds__(256)
void gather_rows(const float* __restrict__ TS, const int* __restrict__ topIdx,
                 float* __restrict__ out) {
    const int row = blockIdx.x;
    const int src = topIdx[row];
    const int tid = threadIdx.x;
    const float4 v = *reinterpret_cast<const float4*>(&TS[(size_t)src * D_S + tid * 4]);
    *reinterpret_cast<float4*>(&out[(size_t)row * D_S + tid * 4]) = v;
}

// ---------------------------------------------------------------------------
extern "C" void kernel_launch(void* const* d_in, const int* in_sizes, int n_in,
                              void* d_out, int out_size, void* d_ws, size_t ws_size,
                              hipStream_t stream) {
    const float* srt      = (const float*)d_in[0];  // [8192,1024]
    const float* comments = (const float*)d_in[1];  // [4096,768]
    const float* Wc       = (const float*)d_in[2];  // [768,1024]
    const float* bc       = (const float*)d_in[3];  // [1024]
    const float* Ws       = (const float*)d_in[4];  // [1024,1024]
    const float* bs       = (const float*)d_in[5];  // [1024]
    float* out = (float*)d_out;

    // workspace layout (~88.2 MB)
    char* p = (char*)d_ws;
    float* t_c = (float*)p;          p += (size_t)B_C * D_S * 4;     // 16 MB
    float* t_s = (float*)p;          p += (size_t)N_SRT * D_S * 4;   // 32 MB
    unsigned short* tc_h = (unsigned short*)p; p += (size_t)B_C * D_S * 2;    // 8 MB
    unsigned short* ts_h = (unsigned short*)p; p += (size_t)N_SRT * D_S * 2;  // 16 MB
    unsigned short* G    = (unsigned short*)p; p += (size_t)B_C * NGRP * 2;   // 16 MB
    int* g8   = (int*)p;             p += (size_t)B_C * PGRP * 4;    // 128 KB
    int* tidx = (int*)p;

    gemm_bias_relu_dual<<<dim3(D_S / 64, B_C / 64), 256, 0, stream>>>(
        comments, Wc, bc, t_c, tc_h, B_C, D_S, D_C);
    gemm_bias_relu_dual<<<dim3(D_S / 64, N_SRT / 64), 256, 0, stream>>>(
        srt, Ws, bs, t_s, ts_h, N_SRT, D_S, D_S);

    scores_filter<<<dim3(N_SRT / 128, B_C / 128), 256, 0, stream>>>(ts_h, tc_h, G);
    top_groups<<<B_C / 4, 256, 0, stream>>>(G, g8);
    refine<<<B_C, 256, 0, stream>>>(t_c, t_s, g8, tidx);
    gather_rows<<<B_C * KSEL, 256, 0, stream>>>(t_s, tidx, out);
}

// Round 3
// 475.648 us; speedup vs baseline: 3.2775x; 1.0892x over previous
//
#include <hip/hip_runtime.h>
#include <math.h>

#define B_C   4096   // comments
#define N_SRT 8192   // srt rows
#define D_C   768
#define D_S   1024
#define KSEL  2
#define NGRP  (N_SRT / 4)   // 2048 groups of 4 consecutive srt rows
#define PGRP  8             // groups refined per comment row (32 candidates)

typedef float  f32x4  __attribute__((ext_vector_type(4)));
typedef short  short8 __attribute__((ext_vector_type(8)));

__device__ inline unsigned short f2bf(float f) {           // RTNE float->bf16
    unsigned u = __float_as_uint(f);
    u += 0x7FFF + ((u >> 16) & 1);
    return (unsigned short)(u >> 16);
}
__device__ inline float bf2f(unsigned short h) {
    return __uint_as_float(((unsigned)h) << 16);
}

#define GLOAD_LDS16(gsrc, ldst)                                                     \
    __builtin_amdgcn_global_load_lds(                                               \
        (const __attribute__((address_space(1))) void*)(gsrc),                      \
        (__attribute__((address_space(3))) void*)(ldst), 16, 0, 0)

// ---------------------------------------------------------------------------
// Kernel 1 (fused, both transforms): C = relu(A @ W + bias) fp32 + bf16 copy.
// 128x128 block, 256 threads, 8x8 micro-tile, BK=16.
// A staged row-major [128][16] via global_load_lds (linear copy, no transpose);
// W staged [16][128] via global_load_lds. A-fragment reads are 4-address
// broadcasts (free); B-fragment reads accept inherent 4-way conflict.
// Blocks [0, NB0) -> comment transform; [NB0, NB0+NB1) -> srt transform.
// N = 1024 for both. K = 768 / 1024.
// ---------------------------------------------------------------------------
#define NB0 ((B_C / 128) * (D_S / 128))     // 256
#define NB1 ((N_SRT / 128) * (D_S / 128))   // 512

__global__ __launch_bounds__(256)
void transform_fused(const float* __restrict__ A0, const float* __restrict__ W0,
                     const float* __restrict__ b0, float* __restrict__ C0,
                     unsigned short* __restrict__ H0,
                     const float* __restrict__ A1, const float* __restrict__ W1,
                     const float* __restrict__ b1, float* __restrict__ C1,
                     unsigned short* __restrict__ H1) {
    __shared__ __align__(16) float As[128][16];   // A rows (row-major chunk)
    __shared__ __align__(16) float Bs[16][128];   // W rows

    const bool p1 = (int)blockIdx.x >= NB0;
    const int  b  = p1 ? (int)blockIdx.x - NB0 : (int)blockIdx.x;
    const float* __restrict__ A = p1 ? A1 : A0;
    const float* __restrict__ W = p1 ? W1 : W0;
    const float* __restrict__ bias = p1 ? b1 : b0;
    float* __restrict__ C = p1 ? C1 : C0;
    unsigned short* __restrict__ H = p1 ? H1 : H0;
    const int K = p1 ? D_S : D_C;

    const int bn = (b & 7) * 128;         // N/128 == 8 for both problems
    const int bm = (b >> 3) * 128;

    const int tid = threadIdx.x;
    const int tx = tid & 15, ty = tid >> 4;

    float acc[8][8] = {};

    for (int k0 = 0; k0 < K; k0 += 16) {
        __syncthreads();   // protect LDS from previous iteration's readers
#pragma unroll
        for (int i = 0; i < 2; ++i) {
            const int idx = tid + i * 256;
            // A: row r, 16B quad q of the 64B k-chunk
            const int r = idx >> 2, q = idx & 3;
            GLOAD_LDS16(A + (size_t)(bm + r) * K + k0 + q * 4,
                        (char*)As + idx * 16);
            // W: row kk, 16B block c of the 512B n-row
            const int kk = idx >> 5, c = (idx & 31) * 4;
            GLOAD_LDS16(W + (size_t)(k0 + kk) * D_S + bn + c,
                        (char*)Bs + idx * 16);
        }
        __syncthreads();

#pragma unroll
        for (int kq = 0; kq < 4; ++kq) {
            f32x4 a4[8];
#pragma unroll
            for (int i = 0; i < 8; ++i)
                a4[i] = *reinterpret_cast<const f32x4*>(&As[ty * 8 + i][kq * 4]);
#pragma unroll
            for (int k2 = 0; k2 < 4; ++k2) {
                const f32x4 bx = *reinterpret_cast<const f32x4*>(&Bs[kq * 4 + k2][tx * 8]);
                const f32x4 by = *reinterpret_cast<const f32x4*>(&Bs[kq * 4 + k2][tx * 8 + 4]);
                const float bv[8] = {bx[0], bx[1], bx[2], bx[3], by[0], by[1], by[2], by[3]};
#pragma unroll
                for (int i = 0; i < 8; ++i) {
                    const float av = a4[i][k2];
#pragma unroll
                    for (int j = 0; j < 8; ++j)
                        acc[i][j] = fmaf(av, bv[j], acc[i][j]);
                }
            }
        }
    }

    // epilogue: bias + relu, fp32 store + bf16 store
    const f32x4 g0 = *reinterpret_cast<const f32x4*>(&bias[bn + tx * 8]);
    const f32x4 g1 = *reinterpret_cast<const f32x4*>(&bias[bn + tx * 8 + 4]);
#pragma unroll
    for (int i = 0; i < 8; ++i) {
        const int m = bm + ty * 8 + i;
        const int n = bn + tx * 8;
        f32x4 o0, o1;
#pragma unroll
        for (int j = 0; j < 4; ++j) {
            o0[j] = fmaxf(acc[i][j]     + g0[j], 0.f);
            o1[j] = fmaxf(acc[i][j + 4] + g1[j], 0.f);
        }
        *reinterpret_cast<f32x4*>(&C[(size_t)m * D_S + n])     = o0;
        *reinterpret_cast<f32x4*>(&C[(size_t)m * D_S + n + 4]) = o1;
        short8 h;
#pragma unroll
        for (int j = 0; j < 4; ++j) {
            h[j]     = (short)f2bf(o0[j]);
            h[j + 4] = (short)f2bf(o1[j]);
        }
        *reinterpret_cast<short8*>(&H[(size_t)m * D_S + n]) = h;
    }
}

// ---------------------------------------------------------------------------
// Kernel 2: bf16 MFMA score filter. Block = 128 srt x 128 comments, 4 waves
// (2x2), each wave a 64x64 tile (4x4 frags of 16x16x32 MFMA). BK=64, LDS
// XOR-swizzled via pre-swizzled global_load_lds sources (both-sides rule).
// Emits per-(comment, 4-wide-n-group) max into G[B_C][NGRP] (bf16).
// ---------------------------------------------------------------------------
__global__ __launch_bounds__(256)
void scores_filter(const unsigned short* __restrict__ TSh,  // [N_SRT][D_S] bf16
                   const unsigned short* __restrict__ TCh,  // [B_C][D_S] bf16
                   unsigned short* __restrict__ G) {        // [B_C][NGRP] bf16
    __shared__ __align__(16) unsigned short sA[128 * 64];   // TS chunk, swizzled
    __shared__ __align__(16) unsigned short sB[128 * 64];   // TC chunk, swizzled
    const int tid  = threadIdx.x;
    const int lane = tid & 63;
    const int w    = tid >> 6;
    const int lr   = lane & 15, lg = lane >> 4;
    const int wn   = w & 1, wc = w >> 1;
    const int n0   = blockIdx.x * 128;
    const int c0   = blockIdx.y * 128;

    const f32x4 vzero = {0.f, 0.f, 0.f, 0.f};
    f32x4 acc[4][4];
#pragma unroll
    for (int i = 0; i < 4; ++i)
#pragma unroll
        for (int j = 0; j < 4; ++j) acc[i][j] = vzero;

    const int sr = tid >> 3;  // staging row within 32-row stripe
    const int sb = tid & 7;   // 16B block within 128B row

    for (int kc = 0; kc < 16; ++kc) {
        const int kb = kc * 64;
        __syncthreads();
#pragma unroll
        for (int i = 0; i < 4; ++i) {
            const int r  = i * 32 + sr;
            const int sw = (sb ^ (r & 7)) * 8;    // inverse-swizzled k element offset
            GLOAD_LDS16(TSh + (size_t)(n0 + r) * D_S + kb + sw,
                        (char*)sA + i * 4096 + tid * 16);
            GLOAD_LDS16(TCh + (size_t)(c0 + r) * D_S + kb + sw,
                        (char*)sB + i * 4096 + tid * 16);
        }
        __syncthreads();
#pragma unroll
        for (int kt = 0; kt < 2; ++kt) {
            short8 a[4], b[4];
#pragma unroll
            for (int t = 0; t < 4; ++t) {
                const int ra = wn * 64 + t * 16 + lr;
                a[t] = *(const short8*)((const char*)sA + ra * 128 +
                                        (((kt * 4 + lg) ^ (ra & 7)) * 16));
                const int rb = wc * 64 + t * 16 + lr;
                b[t] = *(const short8*)((const char*)sB + rb * 128 +
                                        (((kt * 4 + lg) ^ (rb & 7)) * 16));
            }
#pragma unroll
            for (int i = 0; i < 4; ++i)
#pragma unroll
                for (int j = 0; j < 4; ++j)
                    acc[i][j] = __builtin_amdgcn_mfma_f32_16x16x32_bf16(
                        a[i], b[j], acc[i][j], 0, 0, 0);
        }
    }

    // extraction: per-lane j-run is 4 consecutive n => natural 4-wide group max
#pragma unroll
    for (int nt = 0; nt < 4; ++nt) {
        const int n4 = (n0 >> 2) + wn * 16 + nt * 4 + lg;
#pragma unroll
        for (int ct = 0; ct < 4; ++ct) {
            const int c = c0 + wc * 64 + ct * 16 + lr;
            const f32x4 v = acc[nt][ct];
            const float m = fmaxf(fmaxf(v.x, v.y), fmaxf(v.z, v.w));
            G[(size_t)c * NGRP + n4] = f2bf(m);
        }
    }
}

// ---------------------------------------------------------------------------
// Kernel 3: per comment row, top-8 groups by approx group-max (one wave/row).
// ---------------------------------------------------------------------------
__global__ __launch_bounds__(256)
void top_groups(const unsigned short* __restrict__ G, int* __restrict__ g8) {
    const int w = threadIdx.x >> 6, lane = threadIdx.x & 63;
    const int row = blockIdx.x * 4 + w;
    float v[32];
    const unsigned short* gp = G + (size_t)row * NGRP + lane * 32;
#pragma unroll
    for (int i = 0; i < 4; ++i) {
        short8 h = *(const short8*)(gp + i * 8);
#pragma unroll
        for (int j = 0; j < 8; ++j) v[i * 8 + j] = bf2f((unsigned short)h[j]);
    }
    float pv = INFINITY; int pi = -1;   // previous winner in total order
    int gl[8];
#pragma unroll
    for (int k = 0; k < 8; ++k) {
        float bv = -INFINITY; int bi = NGRP;
#pragma unroll
        for (int i = 0; i < 32; ++i) {
            const int idx = lane * 32 + i;
            const bool after  = (v[i] < pv) || (v[i] == pv && idx > pi);
            const bool before = (v[i] > bv) || (v[i] == bv && idx < bi);
            if (after && before) { bv = v[i]; bi = idx; }
        }
#pragma unroll
        for (int off = 32; off >= 1; off >>= 1) {
            const float ov = __shfl_xor(bv, off);
            const int   oi = __shfl_xor(bi, off);
            if ((ov > bv) || (ov == bv && oi < bi)) { bv = ov; bi = oi; }
        }
        gl[k] = bi; pv = bv; pi = bi;
    }
#pragma unroll
    for (int a = 0; a < 8; ++a)
#pragma unroll
        for (int b2 = 0; b2 < 7; ++b2)
            if (gl[b2] > gl[b2 + 1]) { int t = gl[b2]; gl[b2] = gl[b2 + 1]; gl[b2 + 1] = t; }
    if (lane == 0) {
        int4 lo = make_int4(gl[0], gl[1], gl[2], gl[3]);
        int4 hi = make_int4(gl[4], gl[5], gl[6], gl[7]);
        *reinterpret_cast<int4*>(g8 + (size_t)row * 8)     = lo;
        *reinterpret_cast<int4*>(g8 + (size_t)row * 8 + 4) = hi;
    }
}

// ---------------------------------------------------------------------------
// Kernel 4: exact fp32 refine of the 32 candidates per row -> top-2 indices.
// ---------------------------------------------------------------------------
__global__ __launch_bounds__(256)
void refine(const float* __restrict__ t_c, const float* __restrict__ t_s,
            const int* __restrict__ g8, int* __restrict__ tidx) {
    __shared__ float tc[D_S];
    __shared__ float sc[4 * PGRP];
    const int row = blockIdx.x;
    const int tid = threadIdx.x;
    *reinterpret_cast<float4*>(&tc[tid * 4]) =
        *reinterpret_cast<const float4*>(&t_c[(size_t)row * D_S + tid * 4]);
    __syncthreads();
    const int w = tid >> 6, lane = tid & 63;
    float4 c4[4];
#pragma unroll
    for (int q = 0; q < 4; ++q)
        c4[q] = *reinterpret_cast<const float4*>(&tc[lane * 16 + q * 4]);
#pragma unroll
    for (int i = 0; i < 2; ++i) {
        const int slotg = w * 2 + i;
        const int g = g8[(size_t)row * 8 + slotg];
#pragma unroll
        for (int o = 0; o < 4; ++o) {
            const int n = g * 4 + o;
            const float* ts = t_s + (size_t)n * D_S + lane * 16;
            float p = 0.f;
#pragma unroll
            for (int q = 0; q < 4; ++q) {
                const float4 tv = *reinterpret_cast<const float4*>(ts + q * 4);
                p += c4[q].x * tv.x + c4[q].y * tv.y + c4[q].z * tv.z + c4[q].w * tv.w;
            }
#pragma unroll
            for (int off = 32; off >= 1; off >>= 1) p += __shfl_xor(p, off);
            if (lane == 0) sc[slotg * 4 + o] = p;
        }
    }
    __syncthreads();
    if (tid == 0) {
        float v1 = -INFINITY, v2 = -INFINITY; int i1 = 0, i2 = 0;
#pragma unroll
        for (int s = 0; s < 4 * PGRP; ++s) {
            const int n = g8[(size_t)row * 8 + (s >> 2)] * 4 + (s & 3);
            const float v = sc[s];
            if (v > v1)      { v2 = v1; i2 = i1; v1 = v; i1 = n; }
            else if (v > v2) { v2 = v; i2 = n; }
        }
        tidx[row * 2 + 0] = i1;
        tidx[row * 2 + 1] = i2;
    }
}

// ---------------------------------------------------------------------------
// Kernel 5: gather selected transformed-srt rows -> output [B_C, 2, D_S].
// ---------------------------------------------------------------------------
__global__ __launch_bounds__(256)
void gather_rows(const float* __restrict__ TS, const int* __restrict__ topIdx,
                 float* __restrict__ out) {
    const int row = blockIdx.x;
    const int src = topIdx[row];
    const int tid = threadIdx.x;
    const float4 v = *reinterpret_cast<const float4*>(&TS[(size_t)src * D_S + tid * 4]);
    *reinterpret_cast<float4*>(&out[(size_t)row * D_S + tid * 4]) = v;
}

// ---------------------------------------------------------------------------
extern "C" void kernel_launch(void* const* d_in, const int* in_sizes, int n_in,
                              void* d_out, int out_size, void* d_ws, size_t ws_size,
                              hipStream_t stream) {
    const float* srt      = (const float*)d_in[0];  // [8192,1024]
    const float* comments = (const float*)d_in[1];  // [4096,768]
    const float* Wc       = (const float*)d_in[2];  // [768,1024]
    const float* bc       = (const float*)d_in[3];  // [1024]
    const float* Ws       = (const float*)d_in[4];  // [1024,1024]
    const float* bs       = (const float*)d_in[5];  // [1024]
    float* out = (float*)d_out;

    // workspace layout (~88.2 MB)
    char* p = (char*)d_ws;
    float* t_c = (float*)p;          p += (size_t)B_C * D_S * 4;     // 16 MB
    float* t_s = (float*)p;          p += (size_t)N_SRT * D_S * 4;   // 32 MB
    unsigned short* tc_h = (unsigned short*)p; p += (size_t)B_C * D_S * 2;    // 8 MB
    unsigned short* ts_h = (unsigned short*)p; p += (size_t)N_SRT * D_S * 2;  // 16 MB
    unsigned short* G    = (unsigned short*)p; p += (size_t)B_C * NGRP * 2;   // 16 MB
    int* g8   = (int*)p;             p += (size_t)B_C * PGRP * 4;    // 128 KB
    int* tidx = (int*)p;

    // fused fp32 transforms (exact — index selection depends on these)
    transform_fused<<<NB0 + NB1, 256, 0, stream>>>(
        comments, Wc, bc, t_c, tc_h,
        srt,      Ws, bs, t_s, ts_h);

    scores_filter<<<dim3(N_SRT / 128, B_C / 128), 256, 0, stream>>>(ts_h, tc_h, G);
    top_groups<<<B_C / 4, 256, 0, stream>>>(G, g8);
    refine<<<B_C, 256, 0, stream>>>(t_c, t_s, g8, tidx);
    gather_rows<<<B_C * KSEL, 256, 0, stream>>>(t_s, tidx, out);
}

// Round 4
// 472.585 us; speedup vs baseline: 3.2987x; 1.0065x over previous
//
#include <hip/hip_runtime.h>
#include <math.h>

#define B_C   4096   // comments
#define N_SRT 8192   // srt rows
#define D_C   768
#define D_S   1024
#define KSEL  2
#define NGRP  (N_SRT / 4)   // 2048 groups of 4 consecutive srt rows
#define PGRP  8             // groups refined per comment row (32 candidates)

typedef float  f32x4  __attribute__((ext_vector_type(4)));
typedef short  short8 __attribute__((ext_vector_type(8)));

__device__ inline unsigned short f2bf(float f) {           // RTNE float->bf16
    unsigned u = __float_as_uint(f);
    u += 0x7FFF + ((u >> 16) & 1);
    return (unsigned short)(u >> 16);
}
__device__ inline float bf2f(unsigned short h) {
    return __uint_as_float(((unsigned)h) << 16);
}

#define GLOAD_LDS16(gsrc, ldst)                                                     \
    __builtin_amdgcn_global_load_lds(                                               \
        (const __attribute__((address_space(1))) void*)(gsrc),                      \
        (__attribute__((address_space(3))) void*)(ldst), 16, 0, 0)

// ---------------------------------------------------------------------------
// Kernel 1 (fused, both transforms): C = relu(A @ W + bias) fp32 + bf16 copy.
// 128x128 block, 256 threads, 8x8 micro-tile, BK=16, double-buffered LDS
// (one __syncthreads per iter; its implicit vmcnt(0) drains global_load_lds).
// A tile XOR-swizzled (source pre-swizzle + read swizzle, both-sides rule):
//   stored 16B-block q of row r holds global k-block q ^ ((r>>3)&3)
//   -> A-fragment reads (4 ty-addresses/wave, 512B apart) land in 4 distinct
//      banks instead of 1 (was a 4-way broadcast conflict = the round-3 stall).
// W tile [16][128] linear; B-fragment reads keep the inherent 4-way (1.58x).
// ---------------------------------------------------------------------------
#define NB0 ((B_C / 128) * (D_S / 128))     // 256
#define NB1 ((N_SRT / 128) * (D_S / 128))   // 512

__global__ __launch_bounds__(256)
void transform_fused(const float* __restrict__ A0, const float* __restrict__ W0,
                     const float* __restrict__ b0, float* __restrict__ C0,
                     unsigned short* __restrict__ H0,
                     const float* __restrict__ A1, const float* __restrict__ W1,
                     const float* __restrict__ b1, float* __restrict__ C1,
                     unsigned short* __restrict__ H1) {
    __shared__ __align__(16) float As[2][128][16];   // 8KB each, swizzled
    __shared__ __align__(16) float Bs[2][16][128];   // 8KB each, linear

    const bool p1 = (int)blockIdx.x >= NB0;
    const int  b  = p1 ? (int)blockIdx.x - NB0 : (int)blockIdx.x;
    const float* __restrict__ A = p1 ? A1 : A0;
    const float* __restrict__ W = p1 ? W1 : W0;
    const float* __restrict__ bias = p1 ? b1 : b0;
    float* __restrict__ C = p1 ? C1 : C0;
    unsigned short* __restrict__ H = p1 ? H1 : H0;
    const int K = p1 ? D_S : D_C;

    const int bn = (b & 7) * 128;         // N/128 == 8 for both problems
    const int bm = (b >> 3) * 128;

    const int tid = threadIdx.x;
    const int tx = tid & 15, ty = tid >> 4;

    // staging descriptors (2 chunks of 256 threads each)
    // A: idx -> row r=idx>>2, quad q=idx&3, pre-swizzled source block q^((r>>3)&3)
    // W: idx -> row kk=idx>>5, 16B col block (idx&31)
    int a_off[2], w_off[2];
#pragma unroll
    for (int i = 0; i < 2; ++i) {
        const int idx = tid + i * 256;
        const int r = idx >> 2, q = idx & 3;
        a_off[i] = r * K + (q ^ ((r >> 3) & 3)) * 4;   // + bm*K + k0
        w_off[i] = (idx >> 5) * D_S + (idx & 31) * 4;  // + k0*D_S + bn
    }

#define STAGE(bufi, k0)                                                        \
    {                                                                          \
        _Pragma("unroll")                                                      \
        for (int i = 0; i < 2; ++i) {                                          \
            const int idx = tid + i * 256;                                     \
            GLOAD_LDS16(A + (size_t)bm * K + (k0) + a_off[i],                  \
                        (char*)&As[bufi][0][0] + idx * 16);                    \
            GLOAD_LDS16(W + (size_t)(k0) * D_S + bn + w_off[i],                \
                        (char*)&Bs[bufi][0][0] + idx * 16);                    \
        }                                                                      \
    }

    float acc[8][8] = {};

    STAGE(0, 0);
    __syncthreads();                       // drains vmcnt(0) + barrier

    const int nk = K / 16;
    for (int t = 0; t < nk; ++t) {
        const int cur = t & 1;
        if (t + 1 < nk) STAGE(t & 1 ? 0 : 1, (t + 1) * 16);

#pragma unroll
        for (int kq = 0; kq < 4; ++kq) {
            f32x4 a4[8];
#pragma unroll
            for (int i = 0; i < 8; ++i)
                a4[i] = *reinterpret_cast<const f32x4*>(
                    &As[cur][ty * 8 + i][(kq ^ (ty & 3)) * 4]);   // read-side swizzle
#pragma unroll
            for (int k2 = 0; k2 < 4; ++k2) {
                const f32x4 bx = *reinterpret_cast<const f32x4*>(&Bs[cur][kq * 4 + k2][tx * 8]);
                const f32x4 by = *reinterpret_cast<const f32x4*>(&Bs[cur][kq * 4 + k2][tx * 8 + 4]);
                const float bv[8] = {bx[0], bx[1], bx[2], bx[3], by[0], by[1], by[2], by[3]};
#pragma unroll
                for (int i = 0; i < 8; ++i) {
                    const float av = a4[i][k2];
#pragma unroll
                    for (int j = 0; j < 8; ++j)
                        acc[i][j] = fmaf(av, bv[j], acc[i][j]);
                }
            }
        }
        __syncthreads();   // waves done reading buf[cur]; next stage's loads drained
    }
#undef STAGE

    // epilogue: bias + relu, fp32 store + bf16 store
    const f32x4 g0 = *reinterpret_cast<const f32x4*>(&bias[bn + tx * 8]);
    const f32x4 g1 = *reinterpret_cast<const f32x4*>(&bias[bn + tx * 8 + 4]);
#pragma unroll
    for (int i = 0; i < 8; ++i) {
        const int m = bm + ty * 8 + i;
        const int n = bn + tx * 8;
        f32x4 o0, o1;
#pragma unroll
        for (int j = 0; j < 4; ++j) {
            o0[j] = fmaxf(acc[i][j]     + g0[j], 0.f);
            o1[j] = fmaxf(acc[i][j + 4] + g1[j], 0.f);
        }
        *reinterpret_cast<f32x4*>(&C[(size_t)m * D_S + n])     = o0;
        *reinterpret_cast<f32x4*>(&C[(size_t)m * D_S + n + 4]) = o1;
        short8 h;
#pragma unroll
        for (int j = 0; j < 4; ++j) {
            h[j]     = (short)f2bf(o0[j]);
            h[j + 4] = (short)f2bf(o1[j]);
        }
        *reinterpret_cast<short8*>(&H[(size_t)m * D_S + n]) = h;
    }
}

// ---------------------------------------------------------------------------
// Kernel 2: bf16 MFMA score filter. Block = 128 srt x 128 comments, 4 waves
// (2x2), each wave a 64x64 tile (4x4 frags of 16x16x32 MFMA). BK=64, LDS
// XOR-swizzled via pre-swizzled global_load_lds sources (both-sides rule).
// Emits per-(comment, 4-wide-n-group) max into G[B_C][NGRP] (bf16).
// ---------------------------------------------------------------------------
__global__ __launch_bounds__(256)
void scores_filter(const unsigned short* __restrict__ TSh,  // [N_SRT][D_S] bf16
                   const unsigned short* __restrict__ TCh,  // [B_C][D_S] bf16
                   unsigned short* __restrict__ G) {        // [B_C][NGRP] bf16
    __shared__ __align__(16) unsigned short sA[128 * 64];   // TS chunk, swizzled
    __shared__ __align__(16) unsigned short sB[128 * 64];   // TC chunk, swizzled
    const int tid  = threadIdx.x;
    const int lane = tid & 63;
    const int w    = tid >> 6;
    const int lr   = lane & 15, lg = lane >> 4;
    const int wn   = w & 1, wc = w >> 1;
    const int n0   = blockIdx.x * 128;
    const int c0   = blockIdx.y * 128;

    const f32x4 vzero = {0.f, 0.f, 0.f, 0.f};
    f32x4 acc[4][4];
#pragma unroll
    for (int i = 0; i < 4; ++i)
#pragma unroll
        for (int j = 0; j < 4; ++j) acc[i][j] = vzero;

    const int sr = tid >> 3;  // staging row within 32-row stripe
    const int sb = tid & 7;   // 16B block within 128B row

    for (int kc = 0; kc < 16; ++kc) {
        const int kb = kc * 64;
        __syncthreads();
#pragma unroll
        for (int i = 0; i < 4; ++i) {
            const int r  = i * 32 + sr;
            const int sw = (sb ^ (r & 7)) * 8;    // inverse-swizzled k element offset
            GLOAD_LDS16(TSh + (size_t)(n0 + r) * D_S + kb + sw,
                        (char*)sA + i * 4096 + tid * 16);
            GLOAD_LDS16(TCh + (size_t)(c0 + r) * D_S + kb + sw,
                        (char*)sB + i * 4096 + tid * 16);
        }
        __syncthreads();
#pragma unroll
        for (int kt = 0; kt < 2; ++kt) {
            short8 a[4], b[4];
#pragma unroll
            for (int t = 0; t < 4; ++t) {
                const int ra = wn * 64 + t * 16 + lr;
                a[t] = *(const short8*)((const char*)sA + ra * 128 +
                                        (((kt * 4 + lg) ^ (ra & 7)) * 16));
                const int rb = wc * 64 + t * 16 + lr;
                b[t] = *(const short8*)((const char*)sB + rb * 128 +
                                        (((kt * 4 + lg) ^ (rb & 7)) * 16));
            }
#pragma unroll
            for (int i = 0; i < 4; ++i)
#pragma unroll
                for (int j = 0; j < 4; ++j)
                    acc[i][j] = __builtin_amdgcn_mfma_f32_16x16x32_bf16(
                        a[i], b[j], acc[i][j], 0, 0, 0);
        }
    }

    // extraction: per-lane j-run is 4 consecutive n => natural 4-wide group max
#pragma unroll
    for (int nt = 0; nt < 4; ++nt) {
        const int n4 = (n0 >> 2) + wn * 16 + nt * 4 + lg;
#pragma unroll
        for (int ct = 0; ct < 4; ++ct) {
            const int c = c0 + wc * 64 + ct * 16 + lr;
            const f32x4 v = acc[nt][ct];
            const float m = fmaxf(fmaxf(v.x, v.y), fmaxf(v.z, v.w));
            G[(size_t)c * NGRP + n4] = f2bf(m);
        }
    }
}

// ---------------------------------------------------------------------------
// Kernel 3: per comment row, top-8 groups by approx group-max (one wave/row).
// ---------------------------------------------------------------------------
__global__ __launch_bounds__(256)
void top_groups(const unsigned short* __restrict__ G, int* __restrict__ g8) {
    const int w = threadIdx.x >> 6, lane = threadIdx.x & 63;
    const int row = blockIdx.x * 4 + w;
    float v[32];
    const unsigned short* gp = G + (size_t)row * NGRP + lane * 32;
#pragma unroll
    for (int i = 0; i < 4; ++i) {
        short8 h = *(const short8*)(gp + i * 8);
#pragma unroll
        for (int j = 0; j < 8; ++j) v[i * 8 + j] = bf2f((unsigned short)h[j]);
    }
    float pv = INFINITY; int pi = -1;   // previous winner in total order
    int gl[8];
#pragma unroll
    for (int k = 0; k < 8; ++k) {
        float bv = -INFINITY; int bi = NGRP;
#pragma unroll
        for (int i = 0; i < 32; ++i) {
            const int idx = lane * 32 + i;
            const bool after  = (v[i] < pv) || (v[i] == pv && idx > pi);
            const bool before = (v[i] > bv) || (v[i] == bv && idx < bi);
            if (after && before) { bv = v[i]; bi = idx; }
        }
#pragma unroll
        for (int off = 32; off >= 1; off >>= 1) {
            const float ov = __shfl_xor(bv, off);
            const int   oi = __shfl_xor(bi, off);
            if ((ov > bv) || (ov == bv && oi < bi)) { bv = ov; bi = oi; }
        }
        gl[k] = bi; pv = bv; pi = bi;
    }
#pragma unroll
    for (int a = 0; a < 8; ++a)
#pragma unroll
        for (int b2 = 0; b2 < 7; ++b2)
            if (gl[b2] > gl[b2 + 1]) { int t = gl[b2]; gl[b2] = gl[b2 + 1]; gl[b2 + 1] = t; }
    if (lane == 0) {
        int4 lo = make_int4(gl[0], gl[1], gl[2], gl[3]);
        int4 hi = make_int4(gl[4], gl[5], gl[6], gl[7]);
        *reinterpret_cast<int4*>(g8 + (size_t)row * 8)     = lo;
        *reinterpret_cast<int4*>(g8 + (size_t)row * 8 + 4) = hi;
    }
}

// ---------------------------------------------------------------------------
// Kernel 4: exact fp32 refine of the 32 candidates per row -> top-2 indices.
// ---------------------------------------------------------------------------
__global__ __launch_bounds__(256)
void refine(const float* __restrict__ t_c, const float* __restrict__ t_s,
            const int* __restrict__ g8, int* __restrict__ tidx) {
    __shared__ float tc[D_S];
    __shared__ float sc[4 * PGRP];
    const int row = blockIdx.x;
    const int tid = threadIdx.x;
    *reinterpret_cast<float4*>(&tc[tid * 4]) =
        *reinterpret_cast<const float4*>(&t_c[(size_t)row * D_S + tid * 4]);
    __syncthreads();
    const int w = tid >> 6, lane = tid & 63;
    float4 c4[4];
#pragma unroll
    for (int q = 0; q < 4; ++q)
        c4[q] = *reinterpret_cast<const float4*>(&tc[lane * 16 + q * 4]);
#pragma unroll
    for (int i = 0; i < 2; ++i) {
        const int slotg = w * 2 + i;
        const int g = g8[(size_t)row * 8 + slotg];
#pragma unroll
        for (int o = 0; o < 4; ++o) {
            const int n = g * 4 + o;
            const float* ts = t_s + (size_t)n * D_S + lane * 16;
            float p = 0.f;
#pragma unroll
            for (int q = 0; q < 4; ++q) {
                const float4 tv = *reinterpret_cast<const float4*>(ts + q * 4);
                p += c4[q].x * tv.x + c4[q].y * tv.y + c4[q].z * tv.z + c4[q].w * tv.w;
            }
#pragma unroll
            for (int off = 32; off >= 1; off >>= 1) p += __shfl_xor(p, off);
            if (lane == 0) sc[slotg * 4 + o] = p;
        }
    }
    __syncthreads();
    if (tid == 0) {
        float v1 = -INFINITY, v2 = -INFINITY; int i1 = 0, i2 = 0;
#pragma unroll
        for (int s = 0; s < 4 * PGRP; ++s) {
            const int n = g8[(size_t)row * 8 + (s >> 2)] * 4 + (s & 3);
            const float v = sc[s];
            if (v > v1)      { v2 = v1; i2 = i1; v1 = v; i1 = n; }
            else if (v > v2) { v2 = v; i2 = n; }
        }
        tidx[row * 2 + 0] = i1;
        tidx[row * 2 + 1] = i2;
    }
}

// ---------------------------------------------------------------------------
// Kernel 5: gather selected transformed-srt rows -> output [B_C, 2, D_S].
// ---------------------------------------------------------------------------
__global__ __launch_bounds__(256)
void gather_rows(const float* __restrict__ TS, const int* __restrict__ topIdx,
                 float* __restrict__ out) {
    const int row = blockIdx.x;
    const int src = topIdx[row];
    const int tid = threadIdx.x;
    const float4 v = *reinterpret_cast<const float4*>(&TS[(size_t)src * D_S + tid * 4]);
    *reinterpret_cast<float4*>(&out[(size_t)row * D_S + tid * 4]) = v;
}

// ---------------------------------------------------------------------------
extern "C" void kernel_launch(void* const* d_in, const int* in_sizes, int n_in,
                              void* d_out, int out_size, void* d_ws, size_t ws_size,
                              hipStream_t stream) {
    const float* srt      = (const float*)d_in[0];  // [8192,1024]
    const float* comments = (const float*)d_in[1];  // [4096,768]
    const float* Wc       = (const float*)d_in[2];  // [768,1024]
    const float* bc       = (const float*)d_in[3];  // [1024]
    const float* Ws       = (const float*)d_in[4];  // [1024,1024]
    const float* bs       = (const float*)d_in[5];  // [1024]
    float* out = (float*)d_out;

    // workspace layout (~88.2 MB)
    char* p = (char*)d_ws;
    float* t_c = (float*)p;          p += (size_t)B_C * D_S * 4;     // 16 MB
    float* t_s = (float*)p;          p += (size_t)N_SRT * D_S * 4;   // 32 MB
    unsigned short* tc_h = (unsigned short*)p; p += (size_t)B_C * D_S * 2;    // 8 MB
    unsigned short* ts_h = (unsigned short*)p; p += (size_t)N_SRT * D_S * 2;  // 16 MB
    unsigned short* G    = (unsigned short*)p; p += (size_t)B_C * NGRP * 2;   // 16 MB
    int* g8   = (int*)p;             p += (size_t)B_C * PGRP * 4;    // 128 KB
    int* tidx = (int*)p;

    // fused fp32 transforms (exact — index selection depends on these)
    transform_fused<<<NB0 + NB1, 256, 0, stream>>>(
        comments, Wc, bc, t_c, tc_h,
        srt,      Ws, bs, t_s, ts_h);

    scores_filter<<<dim3(N_SRT / 128, B_C / 128), 256, 0, stream>>>(ts_h, tc_h, G);
    top_groups<<<B_C / 4, 256, 0, stream>>>(G, g8);
    refine<<<B_C, 256, 0, stream>>>(t_c, t_s, g8, tidx);
    gather_rows<<<B_C * KSEL, 256, 0, stream>>>(t_s, tidx, out);
}